// Round 1
// baseline (1654.061 us; speedup 1.0000x reference)
//
#include <hip/hip_runtime.h>

// ScaledDotProductAttention: B=2, H=16, S=2048, D=64, fp32.
// attn_bias is per-query broadcast over keys -> softmax-invariant -> ignored.
// Flash-attention, one query row per thread, K/V staged in LDS,
// defer-max online softmax (rescale only when score > m + 8).

#define S_LEN 2048
#define D_DIM 64
#define QBLK  256
#define KVBLK 64
#define QK_SCALE 0.125f  // 64^-0.5

__global__ __launch_bounds__(256) void sdpa_fp32_kernel(
    const float* __restrict__ q,
    const float* __restrict__ k,
    const float* __restrict__ v,
    float* __restrict__ out)
{
    __shared__ float Ks[KVBLK][D_DIM];   // 16 KB
    __shared__ float Vs[KVBLK][D_DIM];   // 16 KB

    const int tid  = threadIdx.x;
    const int bh   = blockIdx.y;                    // 0..31 (B*H)
    const int qrow = blockIdx.x * QBLK + tid;       // query row within head
    const size_t head_off = (size_t)bh * S_LEN * D_DIM;

    // ---- load this thread's q row into registers, pre-scaled ----
    const float4* qp = reinterpret_cast<const float4*>(q + head_off + (size_t)qrow * D_DIM);
    float4 qr[16];
#pragma unroll
    for (int i = 0; i < 16; ++i) {
        float4 t = qp[i];
        t.x *= QK_SCALE; t.y *= QK_SCALE; t.z *= QK_SCALE; t.w *= QK_SCALE;
        qr[i] = t;
    }

    float o[D_DIM];
#pragma unroll
    for (int i = 0; i < D_DIM; ++i) o[i] = 0.0f;
    float m = 0.0f;   // deferred running max (scores ~ N(0,1): rarely updated)
    float l = 0.0f;   // running sum of exp(s - m)

    const float4* kbase = reinterpret_cast<const float4*>(k + head_off);
    const float4* vbase = reinterpret_cast<const float4*>(v + head_off);

    for (int t0 = 0; t0 < S_LEN; t0 += KVBLK) {
        // ---- stage K/V tile: KVBLK*D = 4096 floats = 1024 float4, 256 thr x 4 ----
        const int tile_f4 = t0 * (D_DIM / 4);
#pragma unroll
        for (int i = 0; i < 4; ++i) {
            int idx = tid + i * 256;
            reinterpret_cast<float4*>(&Ks[0][0])[idx] = kbase[tile_f4 + idx];
            reinterpret_cast<float4*>(&Vs[0][0])[idx] = vbase[tile_f4 + idx];
        }
        __syncthreads();

#pragma unroll 2
        for (int kk = 0; kk < KVBLK; ++kk) {
            // ---- QK dot: all lanes read same row -> LDS broadcast ----
            const float4* krow = reinterpret_cast<const float4*>(&Ks[kk][0]);
            float s = 0.0f;
#pragma unroll
            for (int i = 0; i < 16; ++i) {
                float4 kf = krow[i];
                s += qr[i].x * kf.x + qr[i].y * kf.y + qr[i].z * kf.z + qr[i].w * kf.w;
            }

            // ---- deferred-max online softmax ----
            if (__builtin_expect(s > m + 8.0f, 0)) {
                float corr = __expf(m - s);
                l *= corr;
#pragma unroll
                for (int i = 0; i < D_DIM; ++i) o[i] *= corr;
                m = s;
            }
            float p = __expf(s - m);
            l += p;

            const float4* vrow = reinterpret_cast<const float4*>(&Vs[kk][0]);
#pragma unroll
            for (int i = 0; i < 16; ++i) {
                float4 vf = vrow[i];
                o[4*i+0] += p * vf.x;
                o[4*i+1] += p * vf.y;
                o[4*i+2] += p * vf.z;
                o[4*i+3] += p * vf.w;
            }
        }
        __syncthreads();
    }

    // ---- normalize and store ----
    const float inv_l = 1.0f / l;
    float4* op = reinterpret_cast<float4*>(out + head_off + (size_t)qrow * D_DIM);
#pragma unroll
    for (int i = 0; i < 16; ++i) {
        float4 t;
        t.x = o[4*i+0] * inv_l;
        t.y = o[4*i+1] * inv_l;
        t.z = o[4*i+2] * inv_l;
        t.w = o[4*i+3] * inv_l;
        op[i] = t;
    }
}

extern "C" void kernel_launch(void* const* d_in, const int* in_sizes, int n_in,
                              void* d_out, int out_size, void* d_ws, size_t ws_size,
                              hipStream_t stream) {
    const float* q = (const float*)d_in[0];
    const float* k = (const float*)d_in[1];
    const float* v = (const float*)d_in[2];
    // d_in[3] = attn_bias: per-query constant over key axis -> softmax no-op.
    float* out = (float*)d_out;

    dim3 grid(S_LEN / QBLK, 32);  // (q-tiles, B*H)
    dim3 block(QBLK);
    sdpa_fp32_kernel<<<grid, block, 0, stream>>>(q, k, v, out);
}

// Round 2
// 843.019 us; speedup vs baseline: 1.9621x; 1.9621x over previous
//
#include <hip/hip_runtime.h>

// ScaledDotProductAttention: B=2, H=16, S=2048, D=64, fp32.
// attn_bias is per-query broadcast over keys -> softmax-invariant -> ignored.
//
// R1 structure: 4 lanes per q-row (16 dims each) -> no register spill,
// 1024 blocks (16 waves/CU), split dot via 4 accumulators + shfl_xor reduce,
// defer-max online softmax.

#define S_LEN 2048
#define D_DIM 64
#define KVBLK 64
#define ROWS_PER_BLOCK 64
#define QK_SCALE 0.125f  // 64^-0.5

__global__ __launch_bounds__(256, 4) void sdpa_fp32_kernel(
    const float* __restrict__ q,
    const float* __restrict__ k,
    const float* __restrict__ v,
    float* __restrict__ out)
{
    __shared__ float Ks[KVBLK][D_DIM];   // 16 KB
    __shared__ float Vs[KVBLK][D_DIM];   // 16 KB

    const int tid  = threadIdx.x;
    const int lane = tid & 63;
    const int g    = lane & 3;           // dim-group within row (0..3)
    const int d0   = g * 16;             // this lane's first dim
    const int wave = tid >> 6;           // 0..3
    const int row_local = wave * 16 + (lane >> 2);   // 0..63
    const int bh   = blockIdx.y;
    const int qrow = blockIdx.x * ROWS_PER_BLOCK + row_local;
    const size_t head_off = (size_t)bh * S_LEN * D_DIM;

    // ---- this lane's 16 q dims, pre-scaled ----
    const float4* qp = reinterpret_cast<const float4*>(q + head_off + (size_t)qrow * D_DIM + d0);
    float4 qf[4];
#pragma unroll
    for (int i = 0; i < 4; ++i) {
        float4 t = qp[i];
        t.x *= QK_SCALE; t.y *= QK_SCALE; t.z *= QK_SCALE; t.w *= QK_SCALE;
        qf[i] = t;
    }

    float o[16];
#pragma unroll
    for (int i = 0; i < 16; ++i) o[i] = 0.0f;
    float m = 0.0f;   // deferred running max
    float l = 0.0f;   // running sum of exp(s-m)

    const float4* kbase = reinterpret_cast<const float4*>(k + head_off);
    const float4* vbase = reinterpret_cast<const float4*>(v + head_off);

    for (int t0 = 0; t0 < S_LEN; t0 += KVBLK) {
        // ---- stage K/V tile: KVBLK*64 floats = 1024 float4 each ----
        const int tile_f4 = t0 * (D_DIM / 4);
#pragma unroll
        for (int i = 0; i < 4; ++i) {
            int idx = tid + i * 256;
            reinterpret_cast<float4*>(&Ks[0][0])[idx] = kbase[tile_f4 + idx];
            reinterpret_cast<float4*>(&Vs[0][0])[idx] = vbase[tile_f4 + idx];
        }
        __syncthreads();

#pragma unroll 4
        for (int kk = 0; kk < KVBLK; ++kk) {
            // ---- partial dot over this lane's 16 dims, 4 indep chains ----
            const float4* krow = reinterpret_cast<const float4*>(&Ks[kk][d0]);
            float4 k0 = krow[0], k1 = krow[1], k2 = krow[2], k3 = krow[3];
            float a0 = qf[0].x * k0.x + qf[0].y * k0.y + qf[0].z * k0.z + qf[0].w * k0.w;
            float a1 = qf[1].x * k1.x + qf[1].y * k1.y + qf[1].z * k1.z + qf[1].w * k1.w;
            float a2 = qf[2].x * k2.x + qf[2].y * k2.y + qf[2].z * k2.z + qf[2].w * k2.w;
            float a3 = qf[3].x * k3.x + qf[3].y * k3.y + qf[3].z * k3.z + qf[3].w * k3.w;
            float s = (a0 + a1) + (a2 + a3);
            // reduce across the 4-lane dim group
            s += __shfl_xor(s, 1);
            s += __shfl_xor(s, 2);

            // ---- deferred-max online softmax (uniform within 4-lane group) ----
            if (__builtin_expect(s > m + 8.0f, 0)) {
                float corr = __expf(m - s);
                l *= corr;
#pragma unroll
                for (int i = 0; i < 16; ++i) o[i] *= corr;
                m = s;
            }
            float p = __expf(s - m);
            l += p;

            // ---- PV over this lane's 16 dims ----
            const float4* vrow = reinterpret_cast<const float4*>(&Vs[kk][d0]);
            float4 v0 = vrow[0], v1 = vrow[1], v2 = vrow[2], v3 = vrow[3];
            o[ 0] += p * v0.x; o[ 1] += p * v0.y; o[ 2] += p * v0.z; o[ 3] += p * v0.w;
            o[ 4] += p * v1.x; o[ 5] += p * v1.y; o[ 6] += p * v1.z; o[ 7] += p * v1.w;
            o[ 8] += p * v2.x; o[ 9] += p * v2.y; o[10] += p * v2.z; o[11] += p * v2.w;
            o[12] += p * v3.x; o[13] += p * v3.y; o[14] += p * v3.z; o[15] += p * v3.w;
        }
        __syncthreads();
    }

    // ---- normalize and store this lane's 16 dims ----
    const float inv_l = 1.0f / l;
    float4* op = reinterpret_cast<float4*>(out + head_off + (size_t)qrow * D_DIM + d0);
#pragma unroll
    for (int i = 0; i < 4; ++i) {
        float4 t;
        t.x = o[4*i+0] * inv_l;
        t.y = o[4*i+1] * inv_l;
        t.z = o[4*i+2] * inv_l;
        t.w = o[4*i+3] * inv_l;
        op[i] = t;
    }
}

extern "C" void kernel_launch(void* const* d_in, const int* in_sizes, int n_in,
                              void* d_out, int out_size, void* d_ws, size_t ws_size,
                              hipStream_t stream) {
    const float* q = (const float*)d_in[0];
    const float* k = (const float*)d_in[1];
    const float* v = (const float*)d_in[2];
    // d_in[3] = attn_bias: per-query constant over key axis -> softmax no-op.
    float* out = (float*)d_out;

    dim3 grid(S_LEN / ROWS_PER_BLOCK, 32);  // (q-tiles, B*H) = (32, 32)
    dim3 block(256);
    sdpa_fp32_kernel<<<grid, block, 0, stream>>>(q, k, v, out);
}

// Round 3
// 294.089 us; speedup vs baseline: 5.6243x; 2.8665x over previous
//
#include <hip/hip_runtime.h>

// ScaledDotProductAttention: B=2, H=16, S=2048, D=64, fp32 in/out.
// attn_bias is per-query broadcast over keys -> softmax-invariant -> ignored.
//
// MFMA flash attention with split-precision bf16 (hi/lo) for fp32-class accuracy:
//   S^T = K_hi·Q_hi + K_hi·Q_lo + K_lo·Q_hi   (mfma_f32_16x16x16bf16_1k, swapped)
//   O^T = V_hi·P_hi + V_lo·P_hi + V_hi·P_lo
// Swapped QK^T makes the S^T D-layout identical to the PV B-layout (K=16),
// so P feeds PV with no cross-lane movement. K/V staged in LDS as packed
// (bf16hi | bf16lo<<16) u32, XOR-swizzled (byte ^= (row&7)<<4) for
// conflict-free ds_read_b128.

#define S_LEN 2048
#define D_DIM 64
#define KVTILE 64
#define QBLK 64
#define QK_SCALE 0.125f

typedef float f32x4 __attribute__((ext_vector_type(4)));
typedef short s16x4 __attribute__((ext_vector_type(4)));

union FragU { uint2 u; s16x4 s; };

static __device__ __forceinline__ unsigned int pack_hl(float x) {
    unsigned int xb = __float_as_uint(x);
    unsigned int hi = xb & 0xFFFF0000u;
    float lo = x - __uint_as_float(hi);
    unsigned int lob = __float_as_uint(lo);
    return (xb >> 16) | (lob & 0xFFFF0000u);   // low16 = bf16(hi), high16 = bf16(lo)
}

__global__ __launch_bounds__(256, 4) void sdpa_mfma_kernel(
    const float* __restrict__ q,
    const float* __restrict__ k,
    const float* __restrict__ v,
    float* __restrict__ out)
{
    __shared__ unsigned int smem[2 * KVTILE * D_DIM];   // 32 KB
    unsigned int* Kl = smem;                     // [64 keys][64 d] packed hl
    unsigned int* Vt = smem + KVTILE * D_DIM;    // [64 d][64 keys] packed hl

    const int tid  = threadIdx.x;
    const int lane = tid & 63;
    const int w    = tid >> 6;       // warp 0..3
    const int c    = lane & 15;      // q-column / row-within-16
    const int g    = lane >> 4;      // k-group 0..3
    const int bh   = blockIdx.y;
    const int q0   = blockIdx.x * QBLK;
    const size_t head = (size_t)bh * S_LEN * D_DIM;

    // ---- Q B-fragments (hi/lo), scale folded in ----
    FragU qh[4], ql[4];
    {
        const float* qrow = q + head + (size_t)(q0 + w * 16 + c) * D_DIM;
#pragma unroll
        for (int dq = 0; dq < 4; ++dq) {
            float4 t = *(const float4*)(qrow + dq * 16 + g * 4);
            unsigned int p0 = pack_hl(t.x * QK_SCALE);
            unsigned int p1 = pack_hl(t.y * QK_SCALE);
            unsigned int p2 = pack_hl(t.z * QK_SCALE);
            unsigned int p3 = pack_hl(t.w * QK_SCALE);
            qh[dq].u.x = (p0 & 0xFFFFu) | (p1 << 16);
            qh[dq].u.y = (p2 & 0xFFFFu) | (p3 << 16);
            ql[dq].u.x = (p0 >> 16) | (p1 & 0xFFFF0000u);
            ql[dq].u.y = (p2 >> 16) | (p3 & 0xFFFF0000u);
        }
    }

    f32x4 acc[4];
#pragma unroll
    for (int dt = 0; dt < 4; ++dt) acc[dt] = (f32x4){0.f, 0.f, 0.f, 0.f};
    float m = 0.0f;      // deferred running max
    float lsum = 0.0f;   // running softmax denominator

    for (int t0 = 0; t0 < S_LEN; t0 += KVTILE) {
        __syncthreads();   // previous tile's LDS reads complete
        // ---- stage K: [key][d] packed, coalesced global, swizzled b128 writes ----
#pragma unroll
        for (int i = 0; i < 4; ++i) {
            int chunk = tid + i * 256;            // 0..1023
            int key = chunk >> 4;
            int d0  = (chunk & 15) * 4;
            float4 t = *(const float4*)(k + head + (size_t)(t0 + key) * D_DIM + d0);
            uint4 pw = make_uint4(pack_hl(t.x), pack_hl(t.y), pack_hl(t.z), pack_hl(t.w));
            unsigned int byte = ((unsigned)(key * 64 + d0) * 4u) ^ ((unsigned)(key & 7) << 4);
            *(uint4*)((char*)Kl + byte) = pw;
        }
        // ---- stage V transposed: [d][key] packed, lane=key mapping ----
        {
            int key = tid & 63;
            int dbase = (tid >> 6) * 4;
#pragma unroll
            for (int i = 0; i < 4; ++i) {
                int d0 = dbase + i * 16;
                float4 t = *(const float4*)(v + head + (size_t)(t0 + key) * D_DIM + d0);
                unsigned int p[4] = {pack_hl(t.x), pack_hl(t.y), pack_hl(t.z), pack_hl(t.w)};
#pragma unroll
                for (int j = 0; j < 4; ++j) {
                    int d = d0 + j;
                    unsigned int byte = ((unsigned)(d * 64 + key) * 4u) ^ ((unsigned)(d & 7) << 4);
                    *(unsigned int*)((char*)Vt + byte) = p[j];
                }
            }
        }
        __syncthreads();

        for (int s = 0; s < KVTILE / 16; ++s) {
            const int kb = s * 16;
            // ---- QK^T swapped: St[key_in_tile][q], 3 split products x 4 d-quarters ----
            f32x4 st = (f32x4){0.f, 0.f, 0.f, 0.f};
#pragma unroll
            for (int dq = 0; dq < 4; ++dq) {
                int keyr = kb + c;
                unsigned int byte = ((unsigned)(keyr * 64 + dq * 16 + g * 4) * 4u) ^ ((unsigned)(keyr & 7) << 4);
                uint4 kw = *(const uint4*)((const char*)Kl + byte);
                FragU kh, klo;
                kh.u.x  = (kw.x & 0xFFFFu) | (kw.y << 16);
                kh.u.y  = (kw.z & 0xFFFFu) | (kw.w << 16);
                klo.u.x = (kw.x >> 16) | (kw.y & 0xFFFF0000u);
                klo.u.y = (kw.z >> 16) | (kw.w & 0xFFFF0000u);
                st = __builtin_amdgcn_mfma_f32_16x16x16bf16_1k(kh.s,  qh[dq].s, st, 0, 0, 0);
                st = __builtin_amdgcn_mfma_f32_16x16x16bf16_1k(kh.s,  ql[dq].s, st, 0, 0, 0);
                st = __builtin_amdgcn_mfma_f32_16x16x16bf16_1k(klo.s, qh[dq].s, st, 0, 0, 0);
            }

            // ---- defer-max online softmax (per q-column = per lane) ----
            float tmax = fmaxf(fmaxf(st[0], st[1]), fmaxf(st[2], st[3]));
            tmax = fmaxf(tmax, __shfl_xor(tmax, 16));
            tmax = fmaxf(tmax, __shfl_xor(tmax, 32));
            if (tmax > m + 8.0f) {
                float corr = __expf(m - tmax);
                lsum *= corr;
#pragma unroll
                for (int dt = 0; dt < 4; ++dt) acc[dt] *= corr;
                m = tmax;
            }
            float p0 = __expf(st[0] - m);
            float p1 = __expf(st[1] - m);
            float p2 = __expf(st[2] - m);
            float p3 = __expf(st[3] - m);
            float psum = (p0 + p1) + (p2 + p3);
            psum += __shfl_xor(psum, 16);
            psum += __shfl_xor(psum, 32);
            lsum += psum;

            // ---- pack P hi/lo: D-layout == B-layout, no shuffles ----
            unsigned int pb0 = __float_as_uint(p0), pb1 = __float_as_uint(p1);
            unsigned int pb2 = __float_as_uint(p2), pb3 = __float_as_uint(p3);
            FragU ph, plo;
            ph.u.x = (pb0 >> 16) | (pb1 & 0xFFFF0000u);
            ph.u.y = (pb2 >> 16) | (pb3 & 0xFFFF0000u);
            float r0 = p0 - __uint_as_float(pb0 & 0xFFFF0000u);
            float r1 = p1 - __uint_as_float(pb1 & 0xFFFF0000u);
            float r2 = p2 - __uint_as_float(pb2 & 0xFFFF0000u);
            float r3 = p3 - __uint_as_float(pb3 & 0xFFFF0000u);
            plo.u.x = (__float_as_uint(r0) >> 16) | (__float_as_uint(r1) & 0xFFFF0000u);
            plo.u.y = (__float_as_uint(r2) >> 16) | (__float_as_uint(r3) & 0xFFFF0000u);

            // ---- PV: O^T[d][q] += V^T · P^T, 3 split products x 4 d-tiles ----
#pragma unroll
            for (int dt = 0; dt < 4; ++dt) {
                int d = dt * 16 + c;
                unsigned int byte = ((unsigned)(d * 64 + kb + g * 4) * 4u) ^ ((unsigned)(d & 7) << 4);
                uint4 vw = *(const uint4*)((const char*)Vt + byte);
                FragU vh, vlo;
                vh.u.x  = (vw.x & 0xFFFFu) | (vw.y << 16);
                vh.u.y  = (vw.z & 0xFFFFu) | (vw.w << 16);
                vlo.u.x = (vw.x >> 16) | (vw.y & 0xFFFF0000u);
                vlo.u.y = (vw.z >> 16) | (vw.w & 0xFFFF0000u);
                acc[dt] = __builtin_amdgcn_mfma_f32_16x16x16bf16_1k(vh.s,  ph.s,  acc[dt], 0, 0, 0);
                acc[dt] = __builtin_amdgcn_mfma_f32_16x16x16bf16_1k(vlo.s, ph.s,  acc[dt], 0, 0, 0);
                acc[dt] = __builtin_amdgcn_mfma_f32_16x16x16bf16_1k(vh.s,  plo.s, acc[dt], 0, 0, 0);
            }
        }
    }

    // ---- epilogue: normalize, transpose via LDS (stride 68), coalesced store ----
    __syncthreads();   // all LDS reads of last tile done; smem reused as Ob
    float* Ob = (float*)smem;  // [64 q][stride 68]
    const float inv_l = 1.0f / lsum;
    const int qlocal = w * 16 + c;
#pragma unroll
    for (int dt = 0; dt < 4; ++dt) {
        f32x4 o = acc[dt] * inv_l;
        float4 o4; o4.x = o[0]; o4.y = o[1]; o4.z = o[2]; o4.w = o[3];
        *(float4*)(Ob + qlocal * 68 + dt * 16 + g * 4) = o4;
    }
    __syncthreads();
#pragma unroll
    for (int i = 0; i < 4; ++i) {
        int f4 = tid + i * 256;
        int ql2 = f4 >> 4;
        int d0  = (f4 & 15) * 4;
        float4 t = *(const float4*)(Ob + ql2 * 68 + d0);
        *(float4*)(out + head + (size_t)(q0 + ql2) * D_DIM + d0) = t;
    }
}

extern "C" void kernel_launch(void* const* d_in, const int* in_sizes, int n_in,
                              void* d_out, int out_size, void* d_ws, size_t ws_size,
                              hipStream_t stream) {
    const float* q = (const float*)d_in[0];
    const float* k = (const float*)d_in[1];
    const float* v = (const float*)d_in[2];
    // d_in[3] = attn_bias: per-query constant over key axis -> softmax no-op.
    float* out = (float*)d_out;

    dim3 grid(S_LEN / QBLK, 32);  // (q-tiles, B*H) = (32, 32)
    dim3 block(256);
    sdpa_mfma_kernel<<<grid, block, 0, stream>>>(q, k, v, out);
}

// Round 4
// 209.219 us; speedup vs baseline: 7.9059x; 1.4057x over previous
//
#include <hip/hip_runtime.h>

// ScaledDotProductAttention: B=2, H=16, S=2048, D=64, fp32 in/out.
// attn_bias is per-query broadcast over keys -> softmax-invariant -> ignored.
//
// R3 structure: 4 warps x 32 q each (QBLK=128). QK^T uses mfma_f32_16x16x32_bf16
// with split precision (S = Kh*Qh + Kh*Ql + Kl*Qh), K staged in LDS as separate
// hi/lo bf16 planes (direct b128 fragment reads, no unpack). PV uses the proven
// mfma_f32_16x16x16bf16_1k (swapped-QK D-layout == PV B-layout: P needs zero
// cross-lane movement), V staged as single RN-rounded bf16 (O = V*Ph + V*Pl).
// XOR swizzle byte^=((row&7)<<4) on all LDS tiles. Defer-max online softmax.

#define S_LEN 2048
#define D_DIM 64
#define KVTILE 64
#define QBLK 128
#define QK_SCALE 0.125f

typedef short s16x4 __attribute__((ext_vector_type(4)));
typedef short s16x8 __attribute__((ext_vector_type(8)));
typedef float f32x4 __attribute__((ext_vector_type(4)));

union U4S8 { uint4 u; s16x8 s; };
union U2S4 { uint2 u; s16x4 s; };

// (b>>16) | (a & 0xFFFF0000): bf16-trunc pack, element b -> low16, a -> high16
static __device__ __forceinline__ unsigned permhi(unsigned a, unsigned b) {
    return __builtin_amdgcn_perm(a, b, 0x07060302u);
}
static __device__ __forceinline__ unsigned bf16rn(float x) {
    unsigned u = __float_as_uint(x);
    return (u + 0x7FFFu + ((u >> 16) & 1u)) >> 16;
}

__global__ __launch_bounds__(256, 2) void sdpa_mfma2_kernel(
    const float* __restrict__ q, const float* __restrict__ k,
    const float* __restrict__ v, float* __restrict__ out)
{
    __shared__ __align__(16) char smem[QBLK * 68 * 4];  // 34816 B
    char* Khi = smem;                  // [64 key][64 d] bf16 hi, 128B rows, swz
    char* Klo = smem + 8192;           // [64 key][64 d] bf16 lo
    char* Vb  = smem + 16384;          // [64 d][64 key] bf16 rn,  128B rows, swz

    const int tid  = threadIdx.x;
    const int lane = tid & 63;
    const int w    = tid >> 6;        // warp 0..3
    const int c    = lane & 15;
    const int g    = lane >> 4;      // 0..3
    const int bh   = blockIdx.y;
    const int q0   = blockIdx.x * QBLK;
    const size_t head = (size_t)bh * S_LEN * D_DIM;

    // ---- Q fragments hi/lo [c2][dq], B-layout for 16x16x32 (k = g*8+j) ----
    s16x8 qh[2][2], qlo[2][2];
#pragma unroll
    for (int c2 = 0; c2 < 2; ++c2) {
        const float* qp = q + head + (size_t)(q0 + w * 32 + c2 * 16 + c) * D_DIM;
#pragma unroll
        for (int dq = 0; dq < 2; ++dq) {
            float4 t0 = *(const float4*)(qp + dq * 32 + g * 8);
            float4 t1 = *(const float4*)(qp + dq * 32 + g * 8 + 4);
            float e[8] = {t0.x, t0.y, t0.z, t0.w, t1.x, t1.y, t1.z, t1.w};
            unsigned ub[8]; unsigned rb[8];
#pragma unroll
            for (int j = 0; j < 8; ++j) {
                float s = e[j] * QK_SCALE;
                ub[j] = __float_as_uint(s);
                float r = s - __uint_as_float(ub[j] & 0xFFFF0000u);
                rb[j] = __float_as_uint(r);
            }
            U4S8 hi, lo;
            hi.u = make_uint4(permhi(ub[1], ub[0]), permhi(ub[3], ub[2]),
                              permhi(ub[5], ub[4]), permhi(ub[7], ub[6]));
            lo.u = make_uint4(permhi(rb[1], rb[0]), permhi(rb[3], rb[2]),
                              permhi(rb[5], rb[4]), permhi(rb[7], rb[6]));
            qh[c2][dq]  = hi.s;
            qlo[c2][dq] = lo.s;
        }
    }

    f32x4 acc[2][4];
#pragma unroll
    for (int c2 = 0; c2 < 2; ++c2)
#pragma unroll
        for (int dt = 0; dt < 4; ++dt) acc[c2][dt] = (f32x4){0.f, 0.f, 0.f, 0.f};
    float m[2]    = {0.f, 0.f};
    float lsum[2] = {0.f, 0.f};

    for (int t0 = 0; t0 < S_LEN; t0 += KVTILE) {
        __syncthreads();   // previous tile's LDS reads complete
        // ---- stage K hi/lo: chunk = 8 d's of one key; coalesced 32B loads ----
#pragma unroll
        for (int i = 0; i < 2; ++i) {
            int chunk = tid + i * 256;
            int key = chunk >> 3;
            int d0  = (chunk & 7) * 8;
            const float* src = k + head + (size_t)(t0 + key) * D_DIM + d0;
            float4 a = *(const float4*)src;
            float4 b = *(const float4*)(src + 4);
            float e[8] = {a.x, a.y, a.z, a.w, b.x, b.y, b.z, b.w};
            unsigned ub[8]; unsigned rb[8];
#pragma unroll
            for (int j = 0; j < 8; ++j) {
                ub[j] = __float_as_uint(e[j]);
                float r = e[j] - __uint_as_float(ub[j] & 0xFFFF0000u);
                rb[j] = __float_as_uint(r);
            }
            uint4 hi = make_uint4(permhi(ub[1], ub[0]), permhi(ub[3], ub[2]),
                                  permhi(ub[5], ub[4]), permhi(ub[7], ub[6]));
            uint4 lo = make_uint4(permhi(rb[1], rb[0]), permhi(rb[3], rb[2]),
                                  permhi(rb[5], rb[4]), permhi(rb[7], rb[6]));
            unsigned byte = ((unsigned)(key * 128 + d0 * 2)) ^ (((unsigned)key & 7u) << 4);
            *(uint4*)(Khi + byte) = hi;
            *(uint4*)(Klo + byte) = lo;
        }
        // ---- stage V transposed bf16-rn: thread = (key-pair, 8 d's) ----
        {
            int kp = tid & 31;
            int dc = tid >> 5;
            const float* v0p = v + head + (size_t)(t0 + 2 * kp) * D_DIM + dc * 8;
            const float* v1p = v0p + D_DIM;
            float4 a0 = *(const float4*)v0p, a1 = *(const float4*)(v0p + 4);
            float4 b0 = *(const float4*)v1p, b1 = *(const float4*)(v1p + 4);
            float x0[8] = {a0.x, a0.y, a0.z, a0.w, a1.x, a1.y, a1.z, a1.w};
            float x1[8] = {b0.x, b0.y, b0.z, b0.w, b1.x, b1.y, b1.z, b1.w};
#pragma unroll
            for (int j = 0; j < 8; ++j) {
                unsigned wd = bf16rn(x0[j]) | (bf16rn(x1[j]) << 16);
                int d = dc * 8 + j;
                unsigned byte = (unsigned)(d * 128) + (((unsigned)(kp * 4)) ^ ((unsigned)j << 4));
                *(unsigned*)(Vb + byte) = wd;
            }
        }
        __syncthreads();

#pragma unroll
        for (int kb = 0; kb < 2; ++kb) {     // 32-key blocks
            // ---- K fragments (direct b128, no unpack) ----
            s16x8 kh[2][2], kl[2][2];        // [kg][dq]
#pragma unroll
            for (int kg = 0; kg < 2; ++kg)
#pragma unroll
                for (int dq = 0; dq < 2; ++dq) {
                    int keyr = kb * 32 + kg * 16 + c;
                    unsigned byte = ((unsigned)(keyr * 128 + dq * 64 + g * 16)) ^ (((unsigned)c & 7u) << 4);
                    kh[kg][dq] = *(const s16x8*)(Khi + byte);
                    kl[kg][dq] = *(const s16x8*)(Klo + byte);
                }

            // ---- QK^T swapped: St[key][q], 3 split products ----
            f32x4 st[2][2];                  // [c2][kg]
            __builtin_amdgcn_s_setprio(1);
#pragma unroll
            for (int c2 = 0; c2 < 2; ++c2)
#pragma unroll
                for (int kg = 0; kg < 2; ++kg) {
                    f32x4 s = (f32x4){0.f, 0.f, 0.f, 0.f};
#pragma unroll
                    for (int dq = 0; dq < 2; ++dq) {
                        s = __builtin_amdgcn_mfma_f32_16x16x32_bf16(kh[kg][dq], qh[c2][dq],  s, 0, 0, 0);
                        s = __builtin_amdgcn_mfma_f32_16x16x32_bf16(kh[kg][dq], qlo[c2][dq], s, 0, 0, 0);
                        s = __builtin_amdgcn_mfma_f32_16x16x32_bf16(kl[kg][dq], qh[c2][dq],  s, 0, 0, 0);
                    }
                    st[c2][kg] = s;
                }
            __builtin_amdgcn_s_setprio(0);

            // ---- defer-max online softmax + P pack (per c2) ----
            s16x4 ph[2][2], pl[2][2];        // [c2][kg]
#pragma unroll
            for (int c2 = 0; c2 < 2; ++c2) {
                float pv[8] = {st[c2][0][0], st[c2][0][1], st[c2][0][2], st[c2][0][3],
                               st[c2][1][0], st[c2][1][1], st[c2][1][2], st[c2][1][3]};
                float tmax = fmaxf(fmaxf(fmaxf(pv[0], pv[1]), fmaxf(pv[2], pv[3])),
                                   fmaxf(fmaxf(pv[4], pv[5]), fmaxf(pv[6], pv[7])));
                tmax = fmaxf(tmax, __shfl_xor(tmax, 16));
                tmax = fmaxf(tmax, __shfl_xor(tmax, 32));
                if (__builtin_expect(tmax > m[c2] + 8.0f, 0)) {
                    float corr = __expf(m[c2] - tmax);
                    lsum[c2] *= corr;
#pragma unroll
                    for (int dt = 0; dt < 4; ++dt) acc[c2][dt] *= corr;
                    m[c2] = tmax;
                }
                float psum = 0.f;
#pragma unroll
                for (int j = 0; j < 8; ++j) { pv[j] = __expf(pv[j] - m[c2]); psum += pv[j]; }
                psum += __shfl_xor(psum, 16);
                psum += __shfl_xor(psum, 32);
                lsum[c2] += psum;
                unsigned ub[8]; unsigned rb[8];
#pragma unroll
                for (int j = 0; j < 8; ++j) {
                    ub[j] = __float_as_uint(pv[j]);
                    float r = pv[j] - __uint_as_float(ub[j] & 0xFFFF0000u);
                    rb[j] = __float_as_uint(r);
                }
                U2S4 h0, h1, l0, l1;
                h0.u = make_uint2(permhi(ub[1], ub[0]), permhi(ub[3], ub[2]));
                h1.u = make_uint2(permhi(ub[5], ub[4]), permhi(ub[7], ub[6]));
                l0.u = make_uint2(permhi(rb[1], rb[0]), permhi(rb[3], rb[2]));
                l1.u = make_uint2(permhi(rb[5], rb[4]), permhi(rb[7], rb[6]));
                ph[c2][0] = h0.s; ph[c2][1] = h1.s;
                pl[c2][0] = l0.s; pl[c2][1] = l1.s;
            }

            // ---- PV: O^T += V^T·P^T (16x16x16, D-layout == B-layout) ----
            __builtin_amdgcn_s_setprio(1);
#pragma unroll
            for (int kg = 0; kg < 2; ++kg)
#pragma unroll
                for (int dt = 0; dt < 4; ++dt) {
                    int d = dt * 16 + c;
                    unsigned byte = ((unsigned)(d * 128 + (kb * 32 + kg * 16 + g * 4) * 2)) ^ (((unsigned)c & 7u) << 4);
                    s16x4 vf = *(const s16x4*)(Vb + byte);
#pragma unroll
                    for (int c2 = 0; c2 < 2; ++c2) {
                        acc[c2][dt] = __builtin_amdgcn_mfma_f32_16x16x16bf16_1k(vf, ph[c2][kg], acc[c2][dt], 0, 0, 0);
                        acc[c2][dt] = __builtin_amdgcn_mfma_f32_16x16x16bf16_1k(vf, pl[c2][kg], acc[c2][dt], 0, 0, 0);
                    }
                }
            __builtin_amdgcn_s_setprio(0);
        }
    }

    // ---- epilogue: normalize, transpose via LDS (stride 68), coalesced store ----
    __syncthreads();
    float* Ob = (float*)smem;   // [128 q][stride 68]
#pragma unroll
    for (int c2 = 0; c2 < 2; ++c2) {
        float inv = 1.0f / lsum[c2];
        int qlocal = w * 32 + c2 * 16 + c;
#pragma unroll
        for (int dt = 0; dt < 4; ++dt) {
            f32x4 o = acc[c2][dt] * inv;
            float4 o4 = {o[0], o[1], o[2], o[3]};
            *(float4*)(Ob + qlocal * 68 + dt * 16 + g * 4) = o4;
        }
    }
    __syncthreads();
#pragma unroll
    for (int i = 0; i < 8; ++i) {
        int f4 = tid + i * 256;
        int row = f4 >> 4;
        int d0  = (f4 & 15) * 4;
        float4 t = *(const float4*)(Ob + row * 68 + d0);
        *(float4*)(out + head + (size_t)(q0 + row) * D_DIM + d0) = t;
    }
}

extern "C" void kernel_launch(void* const* d_in, const int* in_sizes, int n_in,
                              void* d_out, int out_size, void* d_ws, size_t ws_size,
                              hipStream_t stream) {
    const float* q = (const float*)d_in[0];
    const float* k = (const float*)d_in[1];
    const float* v = (const float*)d_in[2];
    // d_in[3] = attn_bias: per-query constant over key axis -> softmax no-op.
    float* out = (float*)d_out;

    dim3 grid(S_LEN / QBLK, 32);   // (16 q-tiles, 32 heads)
    dim3 block(256);
    sdpa_mfma2_kernel<<<grid, block, 0, stream>>>(q, k, v, out);
}